// Round 5
// baseline (3285.765 us; speedup 1.0000x reference)
//
#include <hip/hip_runtime.h>
#include <stdint.h>

// ---------------------------------------------------------------------------
// Binarized CNN (brevitas M5). Activations after bin_act are exactly +/-1,
// weights exactly +/-0.1  ->  layers 2/3/5 + FC are XNOR-popcount convs
// computed EXACTLY in integers. Only conv1 is a real fp32 conv.
// Stage 1 computed twice (stats pass, sign pass): no y1 materialization.
// R5 restructure: conv1 thread = channel; 84 weights pinned in VGPRs for the
// whole kernel; x broadcast from LDS with diagonal float4 reuse (23 FMA per
// ds_read). R4 post-mortem: old structure spilled (5x VALU bloat), pinned
// at ~294 us regardless of inner-loop edits.
// ---------------------------------------------------------------------------

constexpr int Bn  = 64;
constexpr int H1  = 3980;        // conv1 output rows
constexpr int J1  = 1990;        // after pool2x1
constexpr int H2o = 1991, J2 = 995;
constexpr int H3o = 994,  J3 = 497;
constexpr int H5o = 499,  J5 = 249;
constexpr int FCW = 249 * 8;     // u64 words per FC row (512*249 bits)
constexpr int NB1 = 63;          // conv1 row-blocks (64 rows each, covers 4032)

// ------------------------- weight prep -------------------------------------
// bit = 1  <=>  weight >= 0  <=>  +0.1      (activation bit = 1 <=> +1)
// w1pk: [21][128] float4 -- w1pk[kb][c][jj] = sign(w1[c][4kb+jj]) * 0.1
__global__ void binarize_all(const float* __restrict__ w2, const float* __restrict__ w3,
                             const float* __restrict__ w5, const float* __restrict__ wfc,
                             const float* __restrict__ w1,
                             uint64_t* __restrict__ wb2, uint64_t* __restrict__ wb3,
                             uint64_t* __restrict__ wb5, uint64_t* __restrict__ wbf,
                             float* __restrict__ w1pk)
{
    int idx = blockIdx.x * 256 + threadIdx.x;
    if (idx < 1024) {                                  // w2: [128][128][4] -> [c][k][wdx]
        int wdx = idx & 1, k = (idx >> 1) & 3, c = idx >> 3;
        uint64_t v = 0;
        for (int ci = 0; ci < 64; ++ci)
            if (w2[((size_t)c * 128 + (wdx * 64 + ci)) * 4 + k] >= 0.f) v |= 1ull << ci;
        wb2[idx] = v;
    } else if (idx < 3072) {                           // w3: [256][128][4]
        int t = idx - 1024;
        int wdx = t & 1, k = (t >> 1) & 3, c = t >> 3;
        uint64_t v = 0;
        for (int ci = 0; ci < 64; ++ci)
            if (w3[((size_t)c * 128 + (wdx * 64 + ci)) * 4 + k] >= 0.f) v |= 1ull << ci;
        wb3[t] = v;
    } else if (idx < 9216) {                           // w5: [512][256][3]
        int t = idx - 3072;
        int wdx = t & 3, k = (t >> 2) % 3, c = t / 12;
        uint64_t v = 0;
        for (int ci = 0; ci < 64; ++ci)
            if (w5[((size_t)c * 256 + (wdx * 64 + ci)) * 3 + k] >= 0.f) v |= 1ull << ci;
        wb5[t] = v;
    } else if (idx < 9216 + 69720) {                   // wfc: [35][512*249] -> [oc][hh][wdx]
        int t = idx - 9216;
        int wdx = t & 7, hh = (t >> 3) % 249, oc = t / (249 * 8);
        uint64_t v = 0;
        for (int ci = 0; ci < 64; ++ci)
            if (wfc[(size_t)oc * 127488 + (size_t)(wdx * 64 + ci) * 249 + hh] >= 0.f)
                v |= 1ull << ci;
        wbf[t] = v;
    } else if (idx < 9216 + 69720 + 10752) {           // w1pk: [21][128][4]
        int t  = idx - (9216 + 69720);
        int kb = t >> 9;                // t / 512
        int c  = (t >> 2) & 127;
        int jj = t & 3;
        w1pk[t] = (w1[(size_t)c * 84 + kb * 4 + jj] >= 0.f) ? 0.1f : -0.1f;
    }
}

// ------------------------------- stage 1 ------------------------------------
// conv1 (stride 4, K=84): thread = channel (128/block), 64 rows per block.
// Weights: 21 float4 in VGPRs. x: 85 float4 in LDS, broadcast reads.
// Diagonal reuse: float4 m serves all (row r, kblock kb) with r+kb == m.
// Per-row FMA chain is k ascending 0..83 -> bit-identical across rounds.
// sign_mode==0: per-channel (sum, sumsq) -> part2[block][c] (no reduction).
// sign_mode==1: BN (ref rounding order) + sign + maxpool(2,1) + ballot pack.
__global__ __launch_bounds__(128, 3) void conv1_fused(
    const float* __restrict__ x, const float4* __restrict__ w1pk,
    const float* __restrict__ b1, const float2* __restrict__ bnp,
    const float* __restrict__ g, const float* __restrict__ be,
    float2* __restrict__ part2, uint64_t* __restrict__ a1, const int sign_mode)
{
    __shared__ float4 xs4[85];
    const int n  = blockIdx.y;
    const int bh = blockIdx.x;
    const int h0 = bh << 6;              // first output row of block
    const int c  = threadIdx.x;          // channel

    const float4* x4 = (const float4*)x + (size_t)n * 4000;
    if (c < 85) {
        int gi = h0 + c;                 // float4 index into x (stride-4 conv)
        xs4[c] = (gi < 4000) ? x4[gi] : make_float4(0.f, 0.f, 0.f, 0.f);
    }
    __syncthreads();

    float4 w4[21];
    #pragma unroll
    for (int kb = 0; kb < 21; ++kb) w4[kb] = w1pk[kb * 128 + c];
    const float bv = b1[c];
    float2 mi = make_float2(0.f, 0.f);
    float gg = 0.f, bbe = 0.f;
    if (sign_mode) { mi = bnp[c]; gg = g[c]; bbe = be[c]; }

    float s = 0.f, q = 0.f;

    for (int sb = 0; sb < 8; ++sb) {     // 8 sub-blocks x 8 rows = 64 rows
        float acc[8] = {0.f, 0.f, 0.f, 0.f, 0.f, 0.f, 0.f, 0.f};
        #pragma unroll
        for (int m = 0; m <= 28; ++m) {
            const float4 xv = xs4[sb * 8 + m];
            #pragma unroll
            for (int r = 0; r < 8; ++r) {
                if (m >= r && m - r <= 20) {
                    const float4 wv = w4[m - r];
                    acc[r] = fmaf(wv.x, xv.x, acc[r]);
                    acc[r] = fmaf(wv.y, xv.y, acc[r]);
                    acc[r] = fmaf(wv.z, xv.z, acc[r]);
                    acc[r] = fmaf(wv.w, xv.w, acc[r]);
                }
            }
        }
        const int hbase = h0 + sb * 8;
        if (sign_mode) {
            #pragma unroll
            for (int rp = 0; rp < 4; ++rp) {
                const float v0 = acc[2 * rp]     + bv;
                const float v1 = acc[2 * rp + 1] + bv;
                const float t0 = __fadd_rn(__fmul_rn(__fmul_rn(__fsub_rn(v0, mi.x), mi.y), gg), bbe);
                const float t1 = __fadd_rn(__fmul_rn(__fmul_rn(__fsub_rn(v1, mi.x), mi.y), gg), bbe);
                const uint64_t word = __ballot((t0 >= 0.f) || (t1 >= 0.f));
                const int j = (hbase >> 1) + rp;
                if (j < J1 && (c & 63) == 0)
                    a1[((size_t)n * J1 + j) * 2 + (c >> 6)] = word;
            }
        } else {
            #pragma unroll
            for (int r = 0; r < 8; ++r) {
                if (hbase + r < H1) {
                    const float v = acc[r] + bv;
                    s += v; q = fmaf(v, v, q);
                }
            }
        }
    }

    if (!sign_mode)
        part2[((size_t)n * NB1 + bh) * 128 + c] = make_float2(s, q);
}

// Parallel BN-stat reduce for stage 1: one block per channel (128 blocks).
__global__ __launch_bounds__(256) void bn_reduce1(const float2* __restrict__ part2,
                                                  float2* __restrict__ bnp)
{
    __shared__ double sS[256], sQ[256];
    const int c = blockIdx.x, t = threadIdx.x;
    double S = 0.0, SS = 0.0;
    for (int b = t; b < Bn * NB1; b += 256) {
        const float2 p = part2[(size_t)b * 128 + c];
        S += (double)p.x; SS += (double)p.y;
    }
    sS[t] = S; sQ[t] = SS;
    __syncthreads();
    for (int o = 128; o > 0; o >>= 1) {
        if (t < o) { sS[t] += sS[t + o]; sQ[t] += sQ[t + o]; }
        __syncthreads();
    }
    if (t == 0) {
        const double N = (double)Bn * H1;
        double mu  = sS[0] / N;
        double var = sQ[0] / N - mu * mu;
        bnp[c] = make_float2((float)mu, (float)(1.0 / sqrt(var + 1e-5)));
    }
}

// --------------------------- binary convs ----------------------------------
// q = 64*CINW*V - 2*popc(a xor w) over valid taps; y = 0.1*q + b (exact int q)
template<int CINW, int KK, int PAD, int COUT>
__global__ __launch_bounds__(COUT) void bconv(
    const uint64_t* __restrict__ ain, const uint64_t* __restrict__ wb,
    const int HIN, const int HOUT,
    int16_t* __restrict__ qout, int* __restrict__ part)
{
    __shared__ uint64_t rows[(64 + KK - 1) * CINW];
    const int n  = blockIdx.y;
    const int h0 = blockIdx.x << 6;
    const int c  = threadIdx.x;
    for (int i = c; i < (64 + KK - 1) * CINW; i += COUT) {
        int r = h0 - PAD + i / CINW;
        rows[i] = (r >= 0 && r < HIN) ? ain[((size_t)n * HIN + r) * CINW + (i % CINW)] : 0ull;
    }
    __syncthreads();
    uint64_t wreg[KK * CINW];
    #pragma unroll
    for (int i = 0; i < KK * CINW; ++i) wreg[i] = wb[(size_t)c * KK * CINW + i];
    int sq = 0, sq2 = 0;
    const int hmax = min(64, HOUT - h0);
    for (int i = 0; i < hmax; ++i) {
        const int h   = h0 + i;
        const int klo = max(0, PAD - h);
        const int khi = min(KK, HIN + PAD - h);
        int X = 0;
        if (klo == 0 && khi == KK) {
            #pragma unroll
            for (int k = 0; k < KK; ++k)
                #pragma unroll
                for (int wd = 0; wd < CINW; ++wd)
                    X += __popcll(rows[(i + k) * CINW + wd] ^ wreg[k * CINW + wd]);
        } else {
            for (int k = klo; k < khi; ++k)
                #pragma unroll
                for (int wd = 0; wd < CINW; ++wd)
                    X += __popcll(rows[(i + k) * CINW + wd] ^ wreg[k * CINW + wd]);
        }
        const int q = 64 * CINW * (khi - klo) - 2 * X;
        qout[((size_t)n * HOUT + h) * COUT + c] = (int16_t)q;
        sq += q; sq2 += q * q;
    }
    const size_t blk = (size_t)n * gridDim.x + blockIdx.x;
    part[(blk * COUT + c) * 2 + 0] = sq;
    part[(blk * COUT + c) * 2 + 1] = sq2;
}

// Parallel q-stat reduce: one block per channel; integer sums exact.
__global__ __launch_bounds__(256) void bn_reduce_q(
    const int* __restrict__ part, const int nblk, const int C,
    const double N, const float* __restrict__ bias, float2* __restrict__ bnp)
{
    __shared__ long long sS[256], sQ[256];
    const int c = blockIdx.x, t = threadIdx.x;
    long long Sq = 0, Sq2 = 0;
    for (int b = t; b < nblk; b += 256) {
        const int2 p = *(const int2*)(part + ((size_t)b * C + c) * 2);
        Sq += p.x; Sq2 += p.y;
    }
    sS[t] = Sq; sQ[t] = Sq2;
    __syncthreads();
    for (int o = 128; o > 0; o >>= 1) {
        if (t < o) { sS[t] += sS[t + o]; sQ[t] += sQ[t + o]; }
        __syncthreads();
    }
    if (t == 0) {
        const double bb = (double)bias[c];
        const double S  = 0.1 * (double)sS[0] + N * bb;              // sum(y), exact
        const double SS = 0.01 * (double)sQ[0] + 0.2 * bb * (double)sS[0] + N * bb * bb;
        const double mu = S / N;
        const double var = SS / N - mu * mu;
        bnp[c] = make_float2((float)mu, (float)(1.0 / sqrt(var + 1e-5)));
    }
}

template<int W>
__global__ void signpool_q(const int16_t* __restrict__ q, const float* __restrict__ bias,
                           const float2* __restrict__ bnp, const float* __restrict__ g,
                           const float* __restrict__ be, const int H, const int J,
                           uint64_t* __restrict__ aout)
{
    const int n  = blockIdx.y;
    const int j0 = blockIdx.x << 6;
    const int wave = threadIdx.x >> 6, lane = threadIdx.x & 63;
    const int nw = blockDim.x >> 6;
    const int C  = W * 64;
    const int jend = min(j0 + 64, J);
    for (int w = wave; w < W; w += nw) {
        const int c = (w << 6) + lane;
        const float2 mi = bnp[c];
        const float bb = bias[c], gg = g[c], bbe = be[c];
        for (int j = j0; j < jend; ++j) {
            float y0 = __fadd_rn(__fmul_rn(0.1f, (float)q[((size_t)n * H + 2 * j    ) * C + c]), bb);
            float y1v= __fadd_rn(__fmul_rn(0.1f, (float)q[((size_t)n * H + 2 * j + 1) * C + c]), bb);
            float t0 = __fadd_rn(__fmul_rn(__fmul_rn(__fsub_rn(y0,  mi.x), mi.y), gg), bbe);
            float t1 = __fadd_rn(__fmul_rn(__fmul_rn(__fsub_rn(y1v, mi.x), mi.y), gg), bbe);
            uint64_t word = __ballot((t0 >= 0.f) || (t1 >= 0.f));
            if (lane == 0) aout[((size_t)n * J + j) * W + w] = word;
        }
    }
}

// ------------------------------- FC ----------------------------------------
__global__ void fc_kernel(const uint64_t* __restrict__ a5, const uint64_t* __restrict__ wfcb,
                          float* __restrict__ out)
{
    const int n    = blockIdx.y;
    const int oc   = blockIdx.x * 4 + (threadIdx.x >> 6);
    const int lane = threadIdx.x & 63;
    if (oc >= 35) return;
    const uint64_t* arow = a5   + (size_t)n  * FCW;
    const uint64_t* wrow = wfcb + (size_t)oc * FCW;
    int X = 0;
    for (int i = lane; i < FCW; i += 64)
        X += __popcll(arow[i] ^ wrow[i]);
    for (int o = 32; o > 0; o >>= 1) X += __shfl_xor(X, o, 64);
    if (lane == 0) out[(size_t)n * 35 + oc] = 0.1f * (float)(127488 - 2 * X);
}

// ---------------------------------------------------------------------------
extern "C" void kernel_launch(void* const* d_in, const int* in_sizes, int n_in,
                              void* d_out, int out_size, void* d_ws, size_t ws_size,
                              hipStream_t stream)
{
    (void)in_sizes; (void)n_in; (void)out_size;
    const float* x   = (const float*)d_in[0];
    const float* w1  = (const float*)d_in[1];
    const float* b1  = (const float*)d_in[2];
    const float* g1  = (const float*)d_in[3];
    const float* be1 = (const float*)d_in[4];
    const float* w2  = (const float*)d_in[5];
    const float* b2  = (const float*)d_in[6];
    const float* g2  = (const float*)d_in[7];
    const float* be2 = (const float*)d_in[8];
    const float* w3  = (const float*)d_in[9];
    const float* b3  = (const float*)d_in[10];
    const float* g3  = (const float*)d_in[11];
    const float* be3 = (const float*)d_in[12];
    const float* w5  = (const float*)d_in[13];
    const float* b5  = (const float*)d_in[14];
    const float* g5  = (const float*)d_in[15];
    const float* be5 = (const float*)d_in[16];
    const float* wfc = (const float*)d_in[17];
    char* ws = (char*)d_ws;

    size_t cur = 0;
    auto take = [&](size_t bytes) {
        size_t r = cur;
        cur = (cur + bytes + 255) & ~(size_t)255;
        return r;
    };
    int16_t*  qb  = (int16_t*)(ws + take(33554432));   // stage q buffer (<=32.7 MB)
    int*      pq  = (int*)(ws + take(4194304));        // bconv stat partials
    uint64_t* a1  = (uint64_t*)(ws + take(2037760));
    uint64_t* a2  = (uint64_t*)(ws + take(1018880));
    uint64_t* a3  = (uint64_t*)(ws + take(1017856));
    uint64_t* a5  = (uint64_t*)(ws + take(1019904));
    uint64_t* wb2 = (uint64_t*)(ws + take(8192));
    uint64_t* wb3 = (uint64_t*)(ws + take(16384));
    uint64_t* wb5 = (uint64_t*)(ws + take(49152));
    uint64_t* wbf = (uint64_t*)(ws + take(557760));
    float*    w1pk = (float*)(ws + take(43008));       // signed conv1 weights [21][128][4]
    float2*   p1  = (float2*)(ws + take(4194304));     // 64*63 blocks x 128 float2
    float2*   bnp1 = (float2*)(ws + take(1024));
    float2*   bnp2 = (float2*)(ws + take(1024));
    float2*   bnp3 = (float2*)(ws + take(2048));
    float2*   bnp5 = (float2*)(ws + take(4096));
    if (cur > ws_size) return;   // insufficient workspace -> fail loudly

    hipLaunchKernelGGL(binarize_all, dim3(351), dim3(256), 0, stream,
                       w2, w3, w5, wfc, w1, wb2, wb3, wb5, wbf, w1pk);
    // stage 1: stats pass, reduce, sign pass (no y1 materialization)
    hipLaunchKernelGGL(conv1_fused, dim3(NB1, 64), dim3(128), 0, stream,
                       x, (const float4*)w1pk, b1, (const float2*)nullptr, g1, be1,
                       p1, a1, 0);
    hipLaunchKernelGGL(bn_reduce1, dim3(128), dim3(256), 0, stream, p1, bnp1);
    hipLaunchKernelGGL(conv1_fused, dim3(NB1, 64), dim3(128), 0, stream,
                       x, (const float4*)w1pk, b1, bnp1, g1, be1, p1, a1, 1);
    // stage 2
    hipLaunchKernelGGL((bconv<2, 4, 2, 128>), dim3(32, 64), dim3(128), 0, stream,
                       a1, wb2, J1, H2o, qb, pq);
    hipLaunchKernelGGL(bn_reduce_q, dim3(128), dim3(256), 0, stream,
                       pq, 2048, 128, (double)Bn * H2o, b2, bnp2);
    hipLaunchKernelGGL((signpool_q<2>), dim3(16, 64), dim3(128), 0, stream,
                       qb, b2, bnp2, g2, be2, H2o, J2, a2);
    // stage 3
    hipLaunchKernelGGL((bconv<2, 4, 1, 256>), dim3(16, 64), dim3(256), 0, stream,
                       a2, wb3, J2, H3o, qb, pq);
    hipLaunchKernelGGL(bn_reduce_q, dim3(256), dim3(256), 0, stream,
                       pq, 1024, 256, (double)Bn * H3o, b3, bnp3);
    hipLaunchKernelGGL((signpool_q<4>), dim3(8, 64), dim3(256), 0, stream,
                       qb, b3, bnp3, g3, be3, H3o, J3, a3);
    // stage 5
    hipLaunchKernelGGL((bconv<4, 3, 2, 512>), dim3(8, 64), dim3(512), 0, stream,
                       a3, wb5, J3, H5o, qb, pq);
    hipLaunchKernelGGL(bn_reduce_q, dim3(512), dim3(256), 0, stream,
                       pq, 512, 512, (double)Bn * H5o, b5, bnp5);
    hipLaunchKernelGGL((signpool_q<8>), dim3(4, 64), dim3(256), 0, stream,
                       qb, b5, bnp5, g5, be5, H5o, J5, a5);
    // FC
    hipLaunchKernelGGL(fc_kernel, dim3(9, 64), dim3(256), 0, stream,
                       a5, wbf, (float*)d_out);
}

// Round 6
// 696.884 us; speedup vs baseline: 4.7149x; 4.7149x over previous
//
#include <hip/hip_runtime.h>
#include <stdint.h>

// ---------------------------------------------------------------------------
// Binarized CNN (brevitas M5). Activations after bin_act are exactly +/-1,
// weights exactly +/-0.1  ->  layers 2/3/5 + FC are XNOR-popcount convs
// computed EXACTLY in integers. Only conv1 is a real fp32 conv.
// Stage 1 computed twice (stats pass, sign pass): no y1 materialization.
// R6 restructure after R5 scratch-spill disaster (4.8 GB HBM of spill):
// conv1 thread = row, channels in groups of 8, acc[8] only (~32 VGPR),
// weights via uniform s_load (SGPR), x via one ds_read_b128 per (g,kg).
// No large register arrays -> nothing for the allocator to spill.
// ---------------------------------------------------------------------------

constexpr int Bn  = 64;
constexpr int H1  = 3980;        // conv1 output rows
constexpr int J1  = 1990;        // after pool2x1
constexpr int H2o = 1991, J2 = 995;
constexpr int H3o = 994,  J3 = 497;
constexpr int H5o = 499,  J5 = 249;
constexpr int FCW = 249 * 8;     // u64 words per FC row (512*249 bits)
constexpr int NBX = 16;          // conv1 row-blocks (256 rows each, covers 4096)

// ------------------------- weight prep -------------------------------------
// bit = 1  <=>  weight >= 0  <=>  +0.1      (activation bit = 1 <=> +1)
// w1pk: [16 g][21 kg][8 u] float4 -- sign(w1[g*8+u][kg*4+jj]) * 0.1
__global__ void binarize_all(const float* __restrict__ w2, const float* __restrict__ w3,
                             const float* __restrict__ w5, const float* __restrict__ wfc,
                             const float* __restrict__ w1,
                             uint64_t* __restrict__ wb2, uint64_t* __restrict__ wb3,
                             uint64_t* __restrict__ wb5, uint64_t* __restrict__ wbf,
                             float* __restrict__ w1pk)
{
    int idx = blockIdx.x * 256 + threadIdx.x;
    if (idx < 1024) {                                  // w2: [128][128][4] -> [c][k][wdx]
        int wdx = idx & 1, k = (idx >> 1) & 3, c = idx >> 3;
        uint64_t v = 0;
        for (int ci = 0; ci < 64; ++ci)
            if (w2[((size_t)c * 128 + (wdx * 64 + ci)) * 4 + k] >= 0.f) v |= 1ull << ci;
        wb2[idx] = v;
    } else if (idx < 3072) {                           // w3: [256][128][4]
        int t = idx - 1024;
        int wdx = t & 1, k = (t >> 1) & 3, c = t >> 3;
        uint64_t v = 0;
        for (int ci = 0; ci < 64; ++ci)
            if (w3[((size_t)c * 128 + (wdx * 64 + ci)) * 4 + k] >= 0.f) v |= 1ull << ci;
        wb3[t] = v;
    } else if (idx < 9216) {                           // w5: [512][256][3]
        int t = idx - 3072;
        int wdx = t & 3, k = (t >> 2) % 3, c = t / 12;
        uint64_t v = 0;
        for (int ci = 0; ci < 64; ++ci)
            if (w5[((size_t)c * 256 + (wdx * 64 + ci)) * 3 + k] >= 0.f) v |= 1ull << ci;
        wb5[t] = v;
    } else if (idx < 9216 + 69720) {                   // wfc: [35][512*249] -> [oc][hh][wdx]
        int t = idx - 9216;
        int wdx = t & 7, hh = (t >> 3) % 249, oc = t / (249 * 8);
        uint64_t v = 0;
        for (int ci = 0; ci < 64; ++ci)
            if (wfc[(size_t)oc * 127488 + (size_t)(wdx * 64 + ci) * 249 + hh] >= 0.f)
                v |= 1ull << ci;
        wbf[t] = v;
    } else if (idx < 9216 + 69720 + 10752) {           // w1pk: [16][21][8][4]
        int t  = idx - (9216 + 69720);
        int g  = t / 672, r = t % 672;
        int kg = r >> 5;                 // r / 32
        int e  = r & 31;
        int u  = e >> 2, jj = e & 3;
        w1pk[t] = (w1[(size_t)(g * 8 + u) * 84 + kg * 4 + jj] >= 0.f) ? 0.1f : -0.1f;
    }
}

// ------------------------------- stage 1 ------------------------------------
// conv1 (stride 4, K=84): thread = output row h (256 rows/block).
// x: 276 float4 in LDS; per (group, kg) one ds_read_b128 -> 4 taps, 32 FMA.
// Weights: uniform s_load float4 (SGPR), 8 channels per group, acc[8] only.
// Per-(row,ch) FMA chain is k ascending 0..83 -> bit-identical to R1..R5.
// sign_mode==0: per-channel (sum,sumsq) via shfl tree -> per-block partials.
// sign_mode==1: BN (ref rounding order) + sign + maxpool(2,1); ballot per
//               channel, lane i<32 packs pair-bit into its private (w0,w1).
__global__ __launch_bounds__(256) void conv1_fused(
    const float* __restrict__ x, const float4* __restrict__ w1pk,
    const float* __restrict__ b1, const float2* __restrict__ bnp,
    const float* __restrict__ g1, const float* __restrict__ be1,
    float2* __restrict__ part2, uint64_t* __restrict__ a1, const int sign_mode)
{
    __shared__ float4 xs4[276];
    __shared__ float2 statw[4][128];
    const int n    = blockIdx.y;
    const int h0   = blockIdx.x << 8;    // first output row of block
    const int tid  = threadIdx.x;
    const int wave = tid >> 6, lane = tid & 63;
    const int h    = h0 + tid;
    const bool vh  = h < H1;

    const float4* x4 = (const float4*)x + (size_t)n * 4000;
    for (int i = tid; i < 276; i += 256) {
        const int gi = h0 + i;
        xs4[i] = (gi < 4000) ? x4[gi] : make_float4(0.f, 0.f, 0.f, 0.f);
    }
    __syncthreads();

    uint64_t w0 = 0, w1w = 0;

    for (int g = 0; g < 16; ++g) {
        float acc[8] = {0.f, 0.f, 0.f, 0.f, 0.f, 0.f, 0.f, 0.f};
        const float4* wg = w1pk + g * 168;          // [21][8] float4, uniform
        for (int kg = 0; kg < 21; ++kg) {
            const float4 xv = xs4[tid + kg];
            const float4* wk = wg + kg * 8;
            #pragma unroll
            for (int u = 0; u < 8; ++u) {
                const float4 wv = wk[u];            // uniform -> s_load_dwordx4
                acc[u] = fmaf(wv.x, xv.x, acc[u]);
                acc[u] = fmaf(wv.y, xv.y, acc[u]);
                acc[u] = fmaf(wv.z, xv.z, acc[u]);
                acc[u] = fmaf(wv.w, xv.w, acc[u]);
            }
        }
        if (sign_mode) {
            #pragma unroll
            for (int u = 0; u < 8; ++u) {
                const int c = g * 8 + u;
                const float v = acc[u] + b1[c];
                const float2 mi = bnp[c];
                const float t = __fadd_rn(__fmul_rn(__fmul_rn(__fsub_rn(v, mi.x), mi.y),
                                                    g1[c]), be1[c]);
                const bool sgn = (t >= 0.f) && vh;
                const uint64_t b = __ballot(sgn);
                const uint64_t pb = ((b >> (2 * lane)) | (b >> (2 * lane + 1))) & 1ull;
                if (c < 64) w0  |= pb << c;
                else        w1w |= pb << (c - 64);
            }
        } else {
            #pragma unroll
            for (int u = 0; u < 8; ++u) {
                const int c = g * 8 + u;
                const float v = acc[u] + b1[c];
                float s = vh ? v : 0.f;
                float q = vh ? __fmul_rn(v, v) : 0.f;
                #pragma unroll
                for (int o = 32; o > 0; o >>= 1) {
                    s += __shfl_xor(s, o, 64);
                    q += __shfl_xor(q, o, 64);
                }
                if (lane == 0) statw[wave][c] = make_float2(s, q);
            }
        }
    }

    if (sign_mode) {
        if (lane < 32) {
            const int j = (h0 >> 1) + (wave << 5) + lane;
            if (j < J1) {
                a1[((size_t)n * J1 + j) * 2 + 0] = w0;
                a1[((size_t)n * J1 + j) * 2 + 1] = w1w;
            }
        }
    } else {
        __syncthreads();
        if (tid < 128) {
            const float2 p0 = statw[0][tid], p1v = statw[1][tid];
            const float2 p2 = statw[2][tid], p3 = statw[3][tid];
            part2[((size_t)n * NBX + blockIdx.x) * 128 + tid] =
                make_float2(((p0.x + p1v.x) + p2.x) + p3.x,
                            ((p0.y + p1v.y) + p2.y) + p3.y);
        }
    }
}

// Parallel BN-stat reduce for stage 1: one block per channel (128 blocks).
__global__ __launch_bounds__(256) void bn_reduce1(const float2* __restrict__ part2,
                                                  float2* __restrict__ bnp)
{
    __shared__ double sS[256], sQ[256];
    const int c = blockIdx.x, t = threadIdx.x;
    double S = 0.0, SS = 0.0;
    for (int b = t; b < Bn * NBX; b += 256) {
        const float2 p = part2[(size_t)b * 128 + c];
        S += (double)p.x; SS += (double)p.y;
    }
    sS[t] = S; sQ[t] = SS;
    __syncthreads();
    for (int o = 128; o > 0; o >>= 1) {
        if (t < o) { sS[t] += sS[t + o]; sQ[t] += sQ[t + o]; }
        __syncthreads();
    }
    if (t == 0) {
        const double N = (double)Bn * H1;
        double mu  = sS[0] / N;
        double var = sQ[0] / N - mu * mu;
        bnp[c] = make_float2((float)mu, (float)(1.0 / sqrt(var + 1e-5)));
    }
}

// --------------------------- binary convs ----------------------------------
// q = 64*CINW*V - 2*popc(a xor w) over valid taps; y = 0.1*q + b (exact int q)
template<int CINW, int KK, int PAD, int COUT>
__global__ __launch_bounds__(COUT) void bconv(
    const uint64_t* __restrict__ ain, const uint64_t* __restrict__ wb,
    const int HIN, const int HOUT,
    int16_t* __restrict__ qout, int* __restrict__ part)
{
    __shared__ uint64_t rows[(64 + KK - 1) * CINW];
    const int n  = blockIdx.y;
    const int h0 = blockIdx.x << 6;
    const int c  = threadIdx.x;
    for (int i = c; i < (64 + KK - 1) * CINW; i += COUT) {
        int r = h0 - PAD + i / CINW;
        rows[i] = (r >= 0 && r < HIN) ? ain[((size_t)n * HIN + r) * CINW + (i % CINW)] : 0ull;
    }
    __syncthreads();
    uint64_t wreg[KK * CINW];
    #pragma unroll
    for (int i = 0; i < KK * CINW; ++i) wreg[i] = wb[(size_t)c * KK * CINW + i];
    int sq = 0, sq2 = 0;
    const int hmax = min(64, HOUT - h0);
    for (int i = 0; i < hmax; ++i) {
        const int h   = h0 + i;
        const int klo = max(0, PAD - h);
        const int khi = min(KK, HIN + PAD - h);
        int X = 0;
        if (klo == 0 && khi == KK) {
            #pragma unroll
            for (int k = 0; k < KK; ++k)
                #pragma unroll
                for (int wd = 0; wd < CINW; ++wd)
                    X += __popcll(rows[(i + k) * CINW + wd] ^ wreg[k * CINW + wd]);
        } else {
            for (int k = klo; k < khi; ++k)
                #pragma unroll
                for (int wd = 0; wd < CINW; ++wd)
                    X += __popcll(rows[(i + k) * CINW + wd] ^ wreg[k * CINW + wd]);
        }
        const int q = 64 * CINW * (khi - klo) - 2 * X;
        qout[((size_t)n * HOUT + h) * COUT + c] = (int16_t)q;
        sq += q; sq2 += q * q;
    }
    const size_t blk = (size_t)n * gridDim.x + blockIdx.x;
    part[(blk * COUT + c) * 2 + 0] = sq;
    part[(blk * COUT + c) * 2 + 1] = sq2;
}

// Parallel q-stat reduce: one block per channel; integer sums exact.
__global__ __launch_bounds__(256) void bn_reduce_q(
    const int* __restrict__ part, const int nblk, const int C,
    const double N, const float* __restrict__ bias, float2* __restrict__ bnp)
{
    __shared__ long long sS[256], sQ[256];
    const int c = blockIdx.x, t = threadIdx.x;
    long long Sq = 0, Sq2 = 0;
    for (int b = t; b < nblk; b += 256) {
        const int2 p = *(const int2*)(part + ((size_t)b * C + c) * 2);
        Sq += p.x; Sq2 += p.y;
    }
    sS[t] = Sq; sQ[t] = Sq2;
    __syncthreads();
    for (int o = 128; o > 0; o >>= 1) {
        if (t < o) { sS[t] += sS[t + o]; sQ[t] += sQ[t + o]; }
        __syncthreads();
    }
    if (t == 0) {
        const double bb = (double)bias[c];
        const double S  = 0.1 * (double)sS[0] + N * bb;              // sum(y), exact
        const double SS = 0.01 * (double)sQ[0] + 0.2 * bb * (double)sS[0] + N * bb * bb;
        const double mu = S / N;
        const double var = SS / N - mu * mu;
        bnp[c] = make_float2((float)mu, (float)(1.0 / sqrt(var + 1e-5)));
    }
}

template<int W>
__global__ void signpool_q(const int16_t* __restrict__ q, const float* __restrict__ bias,
                           const float2* __restrict__ bnp, const float* __restrict__ g,
                           const float* __restrict__ be, const int H, const int J,
                           uint64_t* __restrict__ aout)
{
    const int n  = blockIdx.y;
    const int j0 = blockIdx.x << 6;
    const int wave = threadIdx.x >> 6, lane = threadIdx.x & 63;
    const int nw = blockDim.x >> 6;
    const int C  = W * 64;
    const int jend = min(j0 + 64, J);
    for (int w = wave; w < W; w += nw) {
        const int c = (w << 6) + lane;
        const float2 mi = bnp[c];
        const float bb = bias[c], gg = g[c], bbe = be[c];
        for (int j = j0; j < jend; ++j) {
            float y0 = __fadd_rn(__fmul_rn(0.1f, (float)q[((size_t)n * H + 2 * j    ) * C + c]), bb);
            float y1v= __fadd_rn(__fmul_rn(0.1f, (float)q[((size_t)n * H + 2 * j + 1) * C + c]), bb);
            float t0 = __fadd_rn(__fmul_rn(__fmul_rn(__fsub_rn(y0,  mi.x), mi.y), gg), bbe);
            float t1 = __fadd_rn(__fmul_rn(__fmul_rn(__fsub_rn(y1v, mi.x), mi.y), gg), bbe);
            uint64_t word = __ballot((t0 >= 0.f) || (t1 >= 0.f));
            if (lane == 0) aout[((size_t)n * J + j) * W + w] = word;
        }
    }
}

// ------------------------------- FC ----------------------------------------
__global__ void fc_kernel(const uint64_t* __restrict__ a5, const uint64_t* __restrict__ wfcb,
                          float* __restrict__ out)
{
    const int n    = blockIdx.y;
    const int oc   = blockIdx.x * 4 + (threadIdx.x >> 6);
    const int lane = threadIdx.x & 63;
    if (oc >= 35) return;
    const uint64_t* arow = a5   + (size_t)n  * FCW;
    const uint64_t* wrow = wfcb + (size_t)oc * FCW;
    int X = 0;
    for (int i = lane; i < FCW; i += 64)
        X += __popcll(arow[i] ^ wrow[i]);
    for (int o = 32; o > 0; o >>= 1) X += __shfl_xor(X, o, 64);
    if (lane == 0) out[(size_t)n * 35 + oc] = 0.1f * (float)(127488 - 2 * X);
}

// ---------------------------------------------------------------------------
extern "C" void kernel_launch(void* const* d_in, const int* in_sizes, int n_in,
                              void* d_out, int out_size, void* d_ws, size_t ws_size,
                              hipStream_t stream)
{
    (void)in_sizes; (void)n_in; (void)out_size;
    const float* x   = (const float*)d_in[0];
    const float* w1  = (const float*)d_in[1];
    const float* b1  = (const float*)d_in[2];
    const float* g1  = (const float*)d_in[3];
    const float* be1 = (const float*)d_in[4];
    const float* w2  = (const float*)d_in[5];
    const float* b2  = (const float*)d_in[6];
    const float* g2  = (const float*)d_in[7];
    const float* be2 = (const float*)d_in[8];
    const float* w3  = (const float*)d_in[9];
    const float* b3  = (const float*)d_in[10];
    const float* g3  = (const float*)d_in[11];
    const float* be3 = (const float*)d_in[12];
    const float* w5  = (const float*)d_in[13];
    const float* b5  = (const float*)d_in[14];
    const float* g5  = (const float*)d_in[15];
    const float* be5 = (const float*)d_in[16];
    const float* wfc = (const float*)d_in[17];
    char* ws = (char*)d_ws;

    size_t cur = 0;
    auto take = [&](size_t bytes) {
        size_t r = cur;
        cur = (cur + bytes + 255) & ~(size_t)255;
        return r;
    };
    int16_t*  qb  = (int16_t*)(ws + take(33554432));   // stage q buffer (<=32.7 MB)
    int*      pq  = (int*)(ws + take(4194304));        // bconv stat partials
    uint64_t* a1  = (uint64_t*)(ws + take(2037760));
    uint64_t* a2  = (uint64_t*)(ws + take(1018880));
    uint64_t* a3  = (uint64_t*)(ws + take(1017856));
    uint64_t* a5  = (uint64_t*)(ws + take(1019904));
    uint64_t* wb2 = (uint64_t*)(ws + take(8192));
    uint64_t* wb3 = (uint64_t*)(ws + take(16384));
    uint64_t* wb5 = (uint64_t*)(ws + take(49152));
    uint64_t* wbf = (uint64_t*)(ws + take(557760));
    float*    w1pk = (float*)(ws + take(43008));       // signed conv1 weights [16][21][8][4]
    float2*   p1  = (float2*)(ws + take(1048576));     // 64*16 blocks x 128 float2
    float2*   bnp1 = (float2*)(ws + take(1024));
    float2*   bnp2 = (float2*)(ws + take(1024));
    float2*   bnp3 = (float2*)(ws + take(2048));
    float2*   bnp5 = (float2*)(ws + take(4096));
    if (cur > ws_size) return;   // insufficient workspace -> fail loudly

    hipLaunchKernelGGL(binarize_all, dim3(351), dim3(256), 0, stream,
                       w2, w3, w5, wfc, w1, wb2, wb3, wb5, wbf, w1pk);
    // stage 1: stats pass, reduce, sign pass (no y1 materialization)
    hipLaunchKernelGGL(conv1_fused, dim3(NBX, 64), dim3(256), 0, stream,
                       x, (const float4*)w1pk, b1, (const float2*)nullptr, g1, be1,
                       p1, a1, 0);
    hipLaunchKernelGGL(bn_reduce1, dim3(128), dim3(256), 0, stream, p1, bnp1);
    hipLaunchKernelGGL(conv1_fused, dim3(NBX, 64), dim3(256), 0, stream,
                       x, (const float4*)w1pk, b1, bnp1, g1, be1, p1, a1, 1);
    // stage 2
    hipLaunchKernelGGL((bconv<2, 4, 2, 128>), dim3(32, 64), dim3(128), 0, stream,
                       a1, wb2, J1, H2o, qb, pq);
    hipLaunchKernelGGL(bn_reduce_q, dim3(128), dim3(256), 0, stream,
                       pq, 2048, 128, (double)Bn * H2o, b2, bnp2);
    hipLaunchKernelGGL((signpool_q<2>), dim3(16, 64), dim3(128), 0, stream,
                       qb, b2, bnp2, g2, be2, H2o, J2, a2);
    // stage 3
    hipLaunchKernelGGL((bconv<2, 4, 1, 256>), dim3(16, 64), dim3(256), 0, stream,
                       a2, wb3, J2, H3o, qb, pq);
    hipLaunchKernelGGL(bn_reduce_q, dim3(256), dim3(256), 0, stream,
                       pq, 1024, 256, (double)Bn * H3o, b3, bnp3);
    hipLaunchKernelGGL((signpool_q<4>), dim3(8, 64), dim3(256), 0, stream,
                       qb, b3, bnp3, g3, be3, H3o, J3, a3);
    // stage 5
    hipLaunchKernelGGL((bconv<4, 3, 2, 512>), dim3(8, 64), dim3(512), 0, stream,
                       a3, wb5, J3, H5o, qb, pq);
    hipLaunchKernelGGL(bn_reduce_q, dim3(512), dim3(256), 0, stream,
                       pq, 512, 512, (double)Bn * H5o, b5, bnp5);
    hipLaunchKernelGGL((signpool_q<8>), dim3(4, 64), dim3(256), 0, stream,
                       qb, b5, bnp5, g5, be5, H5o, J5, a5);
    // FC
    hipLaunchKernelGGL(fc_kernel, dim3(9, 64), dim3(256), 0, stream,
                       a5, wbf, (float*)d_out);
}

// Round 7
// 417.868 us; speedup vs baseline: 7.8632x; 1.6677x over previous
//
#include <hip/hip_runtime.h>
#include <stdint.h>

// ---------------------------------------------------------------------------
// Binarized CNN (brevitas M5). Activations after bin_act are exactly +/-1,
// weights exactly +/-0.1  ->  layers 2/3/5 + FC are XNOR-popcount convs
// computed EXACTLY in integers. Only conv1 is a real fp32 conv.
// R7: conv1 runs ONCE, stores y1 in coalesced [n][c][h] layout (130 MB).
// Weights are staged in LDS and read as wave-uniform broadcast ds_read_b128
// (R6 post-mortem: global/scalar weight loads stalled the loop at 16% VALU).
// Stats and sign+pool are separate streaming passes over y1.
// ---------------------------------------------------------------------------

constexpr int Bn  = 64;
constexpr int H1  = 3980;        // conv1 output rows
constexpr int J1  = 1990;        // after pool2x1
constexpr int H2o = 1991, J2 = 995;
constexpr int H3o = 994,  J3 = 497;
constexpr int H5o = 499,  J5 = 249;
constexpr int FCW = 249 * 8;     // u64 words per FC row (512*249 bits)

// ------------------------- weight prep -------------------------------------
// bit = 1  <=>  weight >= 0  <=>  +0.1      (activation bit = 1 <=> +1)
// w1pk: [16 G][21 kg][8 u] float4 -- sign(w1[G*8+u][kg*4+jj]) * 0.1
__global__ void binarize_all(const float* __restrict__ w2, const float* __restrict__ w3,
                             const float* __restrict__ w5, const float* __restrict__ wfc,
                             const float* __restrict__ w1,
                             uint64_t* __restrict__ wb2, uint64_t* __restrict__ wb3,
                             uint64_t* __restrict__ wb5, uint64_t* __restrict__ wbf,
                             float* __restrict__ w1pk)
{
    int idx = blockIdx.x * 256 + threadIdx.x;
    if (idx < 1024) {                                  // w2: [128][128][4] -> [c][k][wdx]
        int wdx = idx & 1, k = (idx >> 1) & 3, c = idx >> 3;
        uint64_t v = 0;
        for (int ci = 0; ci < 64; ++ci)
            if (w2[((size_t)c * 128 + (wdx * 64 + ci)) * 4 + k] >= 0.f) v |= 1ull << ci;
        wb2[idx] = v;
    } else if (idx < 3072) {                           // w3: [256][128][4]
        int t = idx - 1024;
        int wdx = t & 1, k = (t >> 1) & 3, c = t >> 3;
        uint64_t v = 0;
        for (int ci = 0; ci < 64; ++ci)
            if (w3[((size_t)c * 128 + (wdx * 64 + ci)) * 4 + k] >= 0.f) v |= 1ull << ci;
        wb3[t] = v;
    } else if (idx < 9216) {                           // w5: [512][256][3]
        int t = idx - 3072;
        int wdx = t & 3, k = (t >> 2) % 3, c = t / 12;
        uint64_t v = 0;
        for (int ci = 0; ci < 64; ++ci)
            if (w5[((size_t)c * 256 + (wdx * 64 + ci)) * 3 + k] >= 0.f) v |= 1ull << ci;
        wb5[t] = v;
    } else if (idx < 9216 + 69720) {                   // wfc: [35][512*249] -> [oc][hh][wdx]
        int t = idx - 9216;
        int wdx = t & 7, hh = (t >> 3) % 249, oc = t / (249 * 8);
        uint64_t v = 0;
        for (int ci = 0; ci < 64; ++ci)
            if (wfc[(size_t)oc * 127488 + (size_t)(wdx * 64 + ci) * 249 + hh] >= 0.f)
                v |= 1ull << ci;
        wbf[t] = v;
    } else if (idx < 9216 + 69720 + 10752) {           // w1pk: [16][21][8][4]
        int t  = idx - (9216 + 69720);
        int G  = t / 672, r = t % 672;
        int kg = r >> 5;
        int e  = r & 31;
        int u  = e >> 2, jj = e & 3;
        w1pk[t] = (w1[(size_t)(G * 8 + u) * 84 + kg * 4 + jj] >= 0.f) ? 0.1f : -0.1f;
    }
}

// ------------------------------- conv1 -------------------------------------
// thread = output row h (256/block), blockIdx.z = channel half (64 ch).
// x: 276 float4 in LDS (lane-stride 16 B reads, 2-way = free).
// w: 8 groups x 21 kg x 8 float4 in LDS, wave-uniform broadcast reads.
// Per-(row,ch) FMA chain is k ascending 0..83 -> bit-identical to R1..R6.
// Stores y1[n][c][h] (+bias), coalesced 4 B/lane.
__global__ __launch_bounds__(256) void conv1_y1(
    const float* __restrict__ x, const float4* __restrict__ w1pk,
    const float* __restrict__ b1, float* __restrict__ y1)
{
    __shared__ float4 xs4[276];
    __shared__ float4 wl[1344];          // [8 g][21 kg][8 u]
    const int n   = blockIdx.y;
    const int h0  = blockIdx.x << 8;
    const int z   = blockIdx.z;
    const int tid = threadIdx.x;
    const int h   = h0 + tid;
    const bool vh = h < H1;

    const float4* x4 = (const float4*)x + (size_t)n * 4000;
    for (int i = tid; i < 276; i += 256) {
        const int gi = h0 + i;
        xs4[i] = (gi < 4000) ? x4[gi] : make_float4(0.f, 0.f, 0.f, 0.f);
    }
    const float4* wsrc = w1pk + (size_t)z * 1344;
    for (int i = tid; i < 1344; i += 256) wl[i] = wsrc[i];
    __syncthreads();

    for (int g = 0; g < 8; ++g) {
        float acc[8] = {0.f, 0.f, 0.f, 0.f, 0.f, 0.f, 0.f, 0.f};
        #pragma unroll 3
        for (int kg = 0; kg < 21; ++kg) {
            const float4 xv = xs4[tid + kg];
            const float4* wk = &wl[(g * 21 + kg) * 8];
            #pragma unroll
            for (int u = 0; u < 8; ++u) {
                const float4 wv = wk[u];             // uniform addr -> broadcast
                acc[u] = fmaf(wv.x, xv.x, acc[u]);
                acc[u] = fmaf(wv.y, xv.y, acc[u]);
                acc[u] = fmaf(wv.z, xv.z, acc[u]);
                acc[u] = fmaf(wv.w, xv.w, acc[u]);
            }
        }
        if (vh) {
            #pragma unroll
            for (int u = 0; u < 8; ++u) {
                const int c = z * 64 + g * 8 + u;
                y1[((size_t)n * 128 + c) * H1 + h] = acc[u] + b1[c];
            }
        }
    }
}

// ---------------------- stage-1 BN stats over y1 ----------------------------
// block = (channel c, batch-slice of 8): streams 8*3980 floats, coalesced.
__global__ __launch_bounds__(256) void bn_stats1(const float* __restrict__ y1,
                                                 double2* __restrict__ part)
{
    __shared__ double sS[256], sQ[256];
    const int c = blockIdx.x, sl = blockIdx.y, t = threadIdx.x;
    double S = 0.0, SS = 0.0;
    for (int i = 0; i < 8; ++i) {
        const int n = sl * 8 + i;
        const float4* p = (const float4*)(y1 + ((size_t)n * 128 + c) * H1);
        for (int m = t; m < 995; m += 256) {
            const float4 v = p[m];
            S  += (double)v.x + (double)v.y + (double)v.z + (double)v.w;
            SS += (double)v.x * v.x + (double)v.y * v.y
                + (double)v.z * v.z + (double)v.w * v.w;
        }
    }
    sS[t] = S; sQ[t] = SS;
    __syncthreads();
    for (int o = 128; o > 0; o >>= 1) {
        if (t < o) { sS[t] += sS[t + o]; sQ[t] += sQ[t + o]; }
        __syncthreads();
    }
    if (t == 0) part[(size_t)c * 8 + sl] = make_double2(sS[0], sQ[0]);
}

__global__ void bn_reduce1(const double2* __restrict__ part, float2* __restrict__ bnp)
{
    const int c = threadIdx.x;                 // 128 threads, 1 block
    double S = 0.0, SS = 0.0;
    for (int sl = 0; sl < 8; ++sl) {
        const double2 p = part[(size_t)c * 8 + sl];
        S += p.x; SS += p.y;
    }
    const double N = (double)Bn * H1;
    const double mu  = S / N;
    const double var = SS / N - mu * mu;
    bnp[c] = make_float2((float)mu, (float)(1.0 / sqrt(var + 1e-5)));
}

// -------------------- stage-1 sign + pool + bitpack -------------------------
// thread = row-pair j; loops c 0..127 reading float2 (rows 2j, 2j+1), builds
// its two 64-channel words in registers. Coalesced 8 B/lane per c.
__global__ __launch_bounds__(256) void signpool1_y(
    const float* __restrict__ y1, const float2* __restrict__ bnp,
    const float* __restrict__ g1, const float* __restrict__ be1,
    uint64_t* __restrict__ a1)
{
    __shared__ float2 smi[128];
    __shared__ float  sg[128], sbe[128];
    const int n   = blockIdx.y;
    const int tid = threadIdx.x;
    const int j   = blockIdx.x * 256 + tid;
    if (tid < 128) { smi[tid] = bnp[tid]; sg[tid] = g1[tid]; sbe[tid] = be1[tid]; }
    __syncthreads();
    if (j >= J1) return;
    uint64_t w0 = 0, w1w = 0;
    for (int c = 0; c < 128; ++c) {
        const float2 v = *(const float2*)(y1 + ((size_t)n * 128 + c) * H1 + 2 * j);
        const float2 mi = smi[c];
        const float gg = sg[c], bb = sbe[c];
        const float t0 = __fadd_rn(__fmul_rn(__fmul_rn(__fsub_rn(v.x, mi.x), mi.y), gg), bb);
        const float t1 = __fadd_rn(__fmul_rn(__fmul_rn(__fsub_rn(v.y, mi.x), mi.y), gg), bb);
        const uint64_t bit = ((t0 >= 0.f) || (t1 >= 0.f)) ? 1ull : 0ull;
        if (c < 64) w0  |= bit << c;
        else        w1w |= bit << (c - 64);
    }
    a1[((size_t)n * J1 + j) * 2 + 0] = w0;
    a1[((size_t)n * J1 + j) * 2 + 1] = w1w;
}

// --------------------------- binary convs ----------------------------------
// q = 64*CINW*V - 2*popc(a xor w) over valid taps; y = 0.1*q + b (exact int q)
template<int CINW, int KK, int PAD, int COUT>
__global__ __launch_bounds__(COUT) void bconv(
    const uint64_t* __restrict__ ain, const uint64_t* __restrict__ wb,
    const int HIN, const int HOUT,
    int16_t* __restrict__ qout, int* __restrict__ part)
{
    __shared__ uint64_t rows[(64 + KK - 1) * CINW];
    const int n  = blockIdx.y;
    const int h0 = blockIdx.x << 6;
    const int c  = threadIdx.x;
    for (int i = c; i < (64 + KK - 1) * CINW; i += COUT) {
        int r = h0 - PAD + i / CINW;
        rows[i] = (r >= 0 && r < HIN) ? ain[((size_t)n * HIN + r) * CINW + (i % CINW)] : 0ull;
    }
    __syncthreads();
    uint64_t wreg[KK * CINW];
    #pragma unroll
    for (int i = 0; i < KK * CINW; ++i) wreg[i] = wb[(size_t)c * KK * CINW + i];
    int sq = 0, sq2 = 0;
    const int hmax = min(64, HOUT - h0);
    for (int i = 0; i < hmax; ++i) {
        const int h   = h0 + i;
        const int klo = max(0, PAD - h);
        const int khi = min(KK, HIN + PAD - h);
        int X = 0;
        if (klo == 0 && khi == KK) {
            #pragma unroll
            for (int k = 0; k < KK; ++k)
                #pragma unroll
                for (int wd = 0; wd < CINW; ++wd)
                    X += __popcll(rows[(i + k) * CINW + wd] ^ wreg[k * CINW + wd]);
        } else {
            for (int k = klo; k < khi; ++k)
                #pragma unroll
                for (int wd = 0; wd < CINW; ++wd)
                    X += __popcll(rows[(i + k) * CINW + wd] ^ wreg[k * CINW + wd]);
        }
        const int q = 64 * CINW * (khi - klo) - 2 * X;
        qout[((size_t)n * HOUT + h) * COUT + c] = (int16_t)q;
        sq += q; sq2 += q * q;
    }
    const size_t blk = (size_t)n * gridDim.x + blockIdx.x;
    part[(blk * COUT + c) * 2 + 0] = sq;
    part[(blk * COUT + c) * 2 + 1] = sq2;
}

// Parallel q-stat reduce: one block per channel; integer sums exact.
__global__ __launch_bounds__(256) void bn_reduce_q(
    const int* __restrict__ part, const int nblk, const int C,
    const double N, const float* __restrict__ bias, float2* __restrict__ bnp)
{
    __shared__ long long sS[256], sQ[256];
    const int c = blockIdx.x, t = threadIdx.x;
    long long Sq = 0, Sq2 = 0;
    for (int b = t; b < nblk; b += 256) {
        const int2 p = *(const int2*)(part + ((size_t)b * C + c) * 2);
        Sq += p.x; Sq2 += p.y;
    }
    sS[t] = Sq; sQ[t] = Sq2;
    __syncthreads();
    for (int o = 128; o > 0; o >>= 1) {
        if (t < o) { sS[t] += sS[t + o]; sQ[t] += sQ[t + o]; }
        __syncthreads();
    }
    if (t == 0) {
        const double bb = (double)bias[c];
        const double S  = 0.1 * (double)sS[0] + N * bb;              // sum(y), exact
        const double SS = 0.01 * (double)sQ[0] + 0.2 * bb * (double)sS[0] + N * bb * bb;
        const double mu = S / N;
        const double var = SS / N - mu * mu;
        bnp[c] = make_float2((float)mu, (float)(1.0 / sqrt(var + 1e-5)));
    }
}

template<int W>
__global__ void signpool_q(const int16_t* __restrict__ q, const float* __restrict__ bias,
                           const float2* __restrict__ bnp, const float* __restrict__ g,
                           const float* __restrict__ be, const int H, const int J,
                           uint64_t* __restrict__ aout)
{
    const int n  = blockIdx.y;
    const int j0 = blockIdx.x << 6;
    const int wave = threadIdx.x >> 6, lane = threadIdx.x & 63;
    const int nw = blockDim.x >> 6;
    const int C  = W * 64;
    const int jend = min(j0 + 64, J);
    for (int w = wave; w < W; w += nw) {
        const int c = (w << 6) + lane;
        const float2 mi = bnp[c];
        const float bb = bias[c], gg = g[c], bbe = be[c];
        for (int j = j0; j < jend; ++j) {
            float y0 = __fadd_rn(__fmul_rn(0.1f, (float)q[((size_t)n * H + 2 * j    ) * C + c]), bb);
            float y1v= __fadd_rn(__fmul_rn(0.1f, (float)q[((size_t)n * H + 2 * j + 1) * C + c]), bb);
            float t0 = __fadd_rn(__fmul_rn(__fmul_rn(__fsub_rn(y0,  mi.x), mi.y), gg), bbe);
            float t1 = __fadd_rn(__fmul_rn(__fmul_rn(__fsub_rn(y1v, mi.x), mi.y), gg), bbe);
            uint64_t word = __ballot((t0 >= 0.f) || (t1 >= 0.f));
            if (lane == 0) aout[((size_t)n * J + j) * W + w] = word;
        }
    }
}

// ------------------------------- FC ----------------------------------------
__global__ void fc_kernel(const uint64_t* __restrict__ a5, const uint64_t* __restrict__ wfcb,
                          float* __restrict__ out)
{
    const int n    = blockIdx.y;
    const int oc   = blockIdx.x * 4 + (threadIdx.x >> 6);
    const int lane = threadIdx.x & 63;
    if (oc >= 35) return;
    const uint64_t* arow = a5   + (size_t)n  * FCW;
    const uint64_t* wrow = wfcb + (size_t)oc * FCW;
    int X = 0;
    for (int i = lane; i < FCW; i += 64)
        X += __popcll(arow[i] ^ wrow[i]);
    for (int o = 32; o > 0; o >>= 1) X += __shfl_xor(X, o, 64);
    if (lane == 0) out[(size_t)n * 35 + oc] = 0.1f * (float)(127488 - 2 * X);
}

// ---------------------------------------------------------------------------
extern "C" void kernel_launch(void* const* d_in, const int* in_sizes, int n_in,
                              void* d_out, int out_size, void* d_ws, size_t ws_size,
                              hipStream_t stream)
{
    (void)in_sizes; (void)n_in; (void)out_size;
    const float* x   = (const float*)d_in[0];
    const float* w1  = (const float*)d_in[1];
    const float* b1  = (const float*)d_in[2];
    const float* g1  = (const float*)d_in[3];
    const float* be1 = (const float*)d_in[4];
    const float* w2  = (const float*)d_in[5];
    const float* b2  = (const float*)d_in[6];
    const float* g2  = (const float*)d_in[7];
    const float* be2 = (const float*)d_in[8];
    const float* w3  = (const float*)d_in[9];
    const float* b3  = (const float*)d_in[10];
    const float* g3  = (const float*)d_in[11];
    const float* be3 = (const float*)d_in[12];
    const float* w5  = (const float*)d_in[13];
    const float* b5  = (const float*)d_in[14];
    const float* g5  = (const float*)d_in[15];
    const float* be5 = (const float*)d_in[16];
    const float* wfc = (const float*)d_in[17];
    char* ws = (char*)d_ws;

    size_t cur = 0;
    auto take = [&](size_t bytes) {
        size_t r = cur;
        cur = (cur + bytes + 255) & ~(size_t)255;
        return r;
    };
    // y1 region (130.4 MB) is reused after signpool1_y: qb (33.6 MB) at +0,
    // pq (4.2 MB) at +34 MB (both first written by stage-2 bconv, which runs
    // after signpool1_y has consumed y1).
    const size_t off_y1 = take(130416640);
    float*    y1  = (float*)(ws + off_y1);
    int16_t*  qb  = (int16_t*)(ws + off_y1);
    int*      pq  = (int*)(ws + off_y1 + 35651584);
    uint64_t* a1  = (uint64_t*)(ws + take(2037760));
    uint64_t* a2  = (uint64_t*)(ws + take(1018880));
    uint64_t* a3  = (uint64_t*)(ws + take(1017856));
    uint64_t* a5  = (uint64_t*)(ws + take(1019904));
    uint64_t* wb2 = (uint64_t*)(ws + take(8192));
    uint64_t* wb3 = (uint64_t*)(ws + take(16384));
    uint64_t* wb5 = (uint64_t*)(ws + take(49152));
    uint64_t* wbf = (uint64_t*)(ws + take(557760));
    float*    w1pk = (float*)(ws + take(43008));       // signed conv1 weights [16][21][8][4]
    double2*  p1  = (double2*)(ws + take(16384));      // 128 ch x 8 slices
    float2*   bnp1 = (float2*)(ws + take(1024));
    float2*   bnp2 = (float2*)(ws + take(1024));
    float2*   bnp3 = (float2*)(ws + take(2048));
    float2*   bnp5 = (float2*)(ws + take(4096));
    if (cur > ws_size) return;   // insufficient workspace -> fail loudly

    hipLaunchKernelGGL(binarize_all, dim3(351), dim3(256), 0, stream,
                       w2, w3, w5, wfc, w1, wb2, wb3, wb5, wbf, w1pk);
    // stage 1: conv once -> y1[n][c][h]; stats pass; sign+pool pass
    hipLaunchKernelGGL(conv1_y1, dim3(16, 64, 2), dim3(256), 0, stream,
                       x, (const float4*)w1pk, b1, y1);
    hipLaunchKernelGGL(bn_stats1, dim3(128, 8), dim3(256), 0, stream, y1, p1);
    hipLaunchKernelGGL(bn_reduce1, dim3(1), dim3(128), 0, stream, p1, bnp1);
    hipLaunchKernelGGL(signpool1_y, dim3(8, 64), dim3(256), 0, stream,
                       y1, bnp1, g1, be1, a1);
    // stage 2
    hipLaunchKernelGGL((bconv<2, 4, 2, 128>), dim3(32, 64), dim3(128), 0, stream,
                       a1, wb2, J1, H2o, qb, pq);
    hipLaunchKernelGGL(bn_reduce_q, dim3(128), dim3(256), 0, stream,
                       pq, 2048, 128, (double)Bn * H2o, b2, bnp2);
    hipLaunchKernelGGL((signpool_q<2>), dim3(16, 64), dim3(128), 0, stream,
                       qb, b2, bnp2, g2, be2, H2o, J2, a2);
    // stage 3
    hipLaunchKernelGGL((bconv<2, 4, 1, 256>), dim3(16, 64), dim3(256), 0, stream,
                       a2, wb3, J2, H3o, qb, pq);
    hipLaunchKernelGGL(bn_reduce_q, dim3(256), dim3(256), 0, stream,
                       pq, 1024, 256, (double)Bn * H3o, b3, bnp3);
    hipLaunchKernelGGL((signpool_q<4>), dim3(8, 64), dim3(256), 0, stream,
                       qb, b3, bnp3, g3, be3, H3o, J3, a3);
    // stage 5
    hipLaunchKernelGGL((bconv<4, 3, 2, 512>), dim3(8, 64), dim3(512), 0, stream,
                       a3, wb5, J3, H5o, qb, pq);
    hipLaunchKernelGGL(bn_reduce_q, dim3(512), dim3(256), 0, stream,
                       pq, 512, 512, (double)Bn * H5o, b5, bnp5);
    hipLaunchKernelGGL((signpool_q<8>), dim3(4, 64), dim3(256), 0, stream,
                       qb, b5, bnp5, g5, be5, H5o, J5, a5);
    // FC
    hipLaunchKernelGGL(fc_kernel, dim3(9, 64), dim3(256), 0, stream,
                       a5, wbf, (float*)d_out);
}